// Round 1
// baseline (115.013 us; speedup 1.0000x reference)
//
#include <hip/hip_runtime.h>

// Problem shape (fixed by reference setup_inputs): B=4, N=M=4096, D=3, fp32.
#define B_    4
#define N_    4096
#define TPB   256
#define SLICE 256   // y-points staged in LDS per block; S = N_/SLICE = 16 slices

// One block: owns TPB points of cloud P (one per thread), scans one SLICE of
// cloud Q staged in LDS, atomicMin's the per-point running min in ws.
// blockIdx.z in [0, 2B): z<B -> x->y direction, else y->x (pointers swapped).
__global__ __launch_bounds__(TPB) void chamfer_dir_kernel(
    const float* __restrict__ x, const float* __restrict__ y,
    unsigned* __restrict__ minx, unsigned* __restrict__ miny)
{
    const int z    = blockIdx.z;
    const int b    = z & (B_ - 1);
    const bool swp = z >= B_;
    const float* P = swp ? y : x;   // cloud whose points we own
    const float* Q = swp ? x : y;   // cloud we scan for nearest neighbor
    unsigned* omin = swp ? miny : minx;

    __shared__ float sq0[SLICE], sq1[SLICE], sq2[SLICE];

    const int tid = threadIdx.x;
    const int n   = blockIdx.y * TPB + tid;

    const float* p = P + ((size_t)b * N_ + n) * 3;
    const float px = p[0], py = p[1], pz = p[2];

    // Stage SLICE points of Q into LDS (SoA). SLICE*3 = 768 floats, 3/thread.
    const int off  = blockIdx.x * SLICE;
    const float* q = Q + ((size_t)b * N_ + off) * 3;
    {
        const float a0 = q[tid * 3 + 0];
        const float a1 = q[tid * 3 + 1];
        const float a2 = q[tid * 3 + 2];
        sq0[tid] = a0; sq1[tid] = a1; sq2[tid] = a2;
    }
    __syncthreads();

    float m = 3.4e38f;
    #pragma unroll 4
    for (int j = 0; j < SLICE; ++j) {
        const float dx = px - sq0[j];
        const float dy = py - sq1[j];
        const float dz = pz - sq2[j];
        float d2 = dx * dx;
        d2 = fmaf(dy, dy, d2);
        d2 = fmaf(dz, dz, d2);
        m = fminf(m, d2);
    }

    // d2 >= 0 by construction -> IEEE bits order as unsigned; ws pre-set to
    // 0xFFFFFFFF (> any float bit pattern) acts as +inf.
    atomicMin(&omin[(size_t)b * N_ + n], __float_as_uint(m));
}

__global__ __launch_bounds__(256) void finalize_kernel(
    const float* __restrict__ minx, const float* __restrict__ miny,
    float* __restrict__ out)
{
    const int tid = threadIdx.x;
    float s0 = 0.0f, s1 = 0.0f;
    for (int i = tid; i < B_ * N_; i += 256) {
        s0 += minx[i];
        s1 += miny[i];
    }
    // wave64 butterfly reduce
    #pragma unroll
    for (int o = 32; o > 0; o >>= 1) {
        s0 += __shfl_down(s0, o);
        s1 += __shfl_down(s1, o);
    }
    __shared__ float ws0[4], ws1[4];
    const int w = tid >> 6;
    if ((tid & 63) == 0) { ws0[w] = s0; ws1[w] = s1; }
    __syncthreads();
    if (tid == 0) {
        const float t0 = ws0[0] + ws0[1] + ws0[2] + ws0[3];
        const float t1 = ws1[0] + ws1[1] + ws1[2] + ws1[3];
        const float inv = 1.0f / (float)(B_ * N_);
        out[0] = fmaxf(t0 * inv, t1 * inv);
    }
}

extern "C" void kernel_launch(void* const* d_in, const int* in_sizes, int n_in,
                              void* d_out, int out_size, void* d_ws, size_t ws_size,
                              hipStream_t stream)
{
    const float* x = (const float*)d_in[0];
    const float* y = (const float*)d_in[1];
    float* out = (float*)d_out;

    unsigned* minx = (unsigned*)d_ws;           // B_*N_ words
    unsigned* miny = minx + B_ * N_;            // B_*N_ words

    // 0xFFFFFFFF > any non-negative float's bit pattern: +inf for atomicMin.
    hipMemsetAsync(d_ws, 0xFF, (size_t)2 * B_ * N_ * sizeof(unsigned), stream);

    dim3 grid(N_ / SLICE, N_ / TPB, 2 * B_);    // 16 x 16 x 8 = 2048 blocks
    chamfer_dir_kernel<<<grid, TPB, 0, stream>>>(x, y, minx, miny);

    finalize_kernel<<<1, 256, 0, stream>>>(
        (const float*)minx, (const float*)miny, out);
}

// Round 2
// 77.041 us; speedup vs baseline: 1.4929x; 1.4929x over previous
//
#include <hip/hip_runtime.h>

// B=4, N=M=4096, D=3, fp32 (fixed by reference setup_inputs).
#define B_   4
#define N_   4096
#define BN_  (B_ * N_)          // 16384 points per cloud
#define TPB  256

// ws layout:
//   float4 packed[2][B][N]   : (qx,qy,qz, 0.5*|q|^2)        512 KB
//   uint   mins  [2][B][N]   : ordered-int-encoded running min  128 KB
// dir 0 (x->y) mins live in mins[0] (per x point), dir 1 in mins[1].

__device__ __forceinline__ unsigned enc_ord(float f) {
    // monotonic float->uint map (handles negatives)
    int b = __float_as_int(f);
    return (unsigned)(b ^ ((b >> 31) | 0x80000000));
}
__device__ __forceinline__ float dec_ord(unsigned u) {
    int b = (u & 0x80000000u) ? (int)(u ^ 0x80000000u) : ~(int)u;
    return __int_as_float(b);
}

__global__ __launch_bounds__(TPB) void pack_kernel(
    const float* __restrict__ x, const float* __restrict__ y,
    float4* __restrict__ pk, unsigned* __restrict__ mins)
{
    const int gid = blockIdx.x * TPB + threadIdx.x;   // [0, 2*BN)
    const float* src = (gid < BN_) ? x : y;
    const int idx = gid & (BN_ - 1);
    const float a0 = src[idx * 3 + 0];
    const float a1 = src[idx * 3 + 1];
    const float a2 = src[idx * 3 + 2];
    const float hqq = 0.5f * (a0 * a0 + a1 * a1 + a2 * a2);
    pk[gid] = make_float4(a0, a1, a2, hqq);
    mins[gid] = 0xFFFFFFFFu;                          // +inf in encoded order
}

// grid: (16 slices of Q, 8 groups of 512 P-points, 2B directions)
// each thread owns 2 P points, scans 256 Q points via uniform (scalar) loads.
__global__ __launch_bounds__(TPB) void chamfer_kernel(
    const float4* __restrict__ pk, unsigned* __restrict__ mins)
{
    const int z    = blockIdx.z;
    const int b    = z & (B_ - 1);
    const bool swp = z >= B_;
    const float4* pkP = pk + (swp ? BN_ : 0) + b * N_;
    const float4* pkQ = pk + (swp ? 0 : BN_) + b * N_;
    unsigned*    omin = mins + (swp ? BN_ : 0) + b * N_;

    const int tid = threadIdx.x;
    const int n0  = blockIdx.y * (2 * TPB) + tid;
    const int n1  = n0 + TPB;

    const float4 p0 = pkP[n0];
    const float4 p1 = pkP[n1];

    const float4* q = pkQ + blockIdx.x * 256;   // wave-uniform base

    float m0 = 3.4e38f, m1 = 3.4e38f;
    #pragma unroll 8
    for (int j = 0; j < 256; ++j) {
        const float4 qq = q[j];                 // uniform -> s_load_dwordx4
        const float e0 = fmaf(-p0.x, qq.x,
                         fmaf(-p0.y, qq.y,
                         fmaf(-p0.z, qq.z, qq.w)));
        const float e1 = fmaf(-p1.x, qq.x,
                         fmaf(-p1.y, qq.y,
                         fmaf(-p1.z, qq.z, qq.w)));
        m0 = fminf(m0, e0);
        m1 = fminf(m1, e1);
    }

    // d2 = pp + 2*e = 2*(e + 0.5pp); clamp happens after global min (monotone).
    const float d0 = (m0 + p0.w) * 2.0f;
    const float d1 = (m1 + p1.w) * 2.0f;
    atomicMin(&omin[n0], enc_ord(d0));
    atomicMin(&omin[n1], enc_ord(d1));
}

__global__ __launch_bounds__(1024) void finalize_kernel(
    const unsigned* __restrict__ mins, float* __restrict__ out)
{
    const int tid = threadIdx.x;
    const uint4* m4 = (const uint4*)mins;       // [2*BN/4] = 8192 uint4
    float s0 = 0.0f, s1 = 0.0f;
    #pragma unroll
    for (int i = 0; i < BN_ / 4; i += 1024) {   // 4 iters
        const uint4 a = m4[i + tid];
        s0 += fmaxf(dec_ord(a.x), 0.0f) + fmaxf(dec_ord(a.y), 0.0f)
            + fmaxf(dec_ord(a.z), 0.0f) + fmaxf(dec_ord(a.w), 0.0f);
        const uint4 c = m4[BN_ / 4 + i + tid];
        s1 += fmaxf(dec_ord(c.x), 0.0f) + fmaxf(dec_ord(c.y), 0.0f)
            + fmaxf(dec_ord(c.z), 0.0f) + fmaxf(dec_ord(c.w), 0.0f);
    }
    #pragma unroll
    for (int o = 32; o > 0; o >>= 1) {
        s0 += __shfl_down(s0, o);
        s1 += __shfl_down(s1, o);
    }
    __shared__ float w0[16], w1[16];
    const int w = tid >> 6;
    if ((tid & 63) == 0) { w0[w] = s0; w1[w] = s1; }
    __syncthreads();
    if (tid == 0) {
        float t0 = 0.0f, t1 = 0.0f;
        #pragma unroll
        for (int i = 0; i < 16; ++i) { t0 += w0[i]; t1 += w1[i]; }
        const float inv = 1.0f / (float)BN_;
        out[0] = fmaxf(t0 * inv, t1 * inv);
    }
}

extern "C" void kernel_launch(void* const* d_in, const int* in_sizes, int n_in,
                              void* d_out, int out_size, void* d_ws, size_t ws_size,
                              hipStream_t stream)
{
    const float* x = (const float*)d_in[0];
    const float* y = (const float*)d_in[1];
    float* out = (float*)d_out;

    float4*   pk   = (float4*)d_ws;                    // 2*BN float4
    unsigned* mins = (unsigned*)(pk + 2 * BN_);        // 2*BN uint

    pack_kernel<<<2 * BN_ / TPB, TPB, 0, stream>>>(x, y, pk, mins);

    dim3 grid(N_ / 256, N_ / (2 * TPB), 2 * B_);       // 16 x 8 x 8 = 1024
    chamfer_kernel<<<grid, TPB, 0, stream>>>(pk, mins);

    finalize_kernel<<<1, 1024, 0, stream>>>(mins, out);
}